// Round 4
// baseline (315.894 us; speedup 1.0000x reference)
//
#include <hip/hip_runtime.h>
#include <math.h>

#define SEQ   2048
#define DM    1024
#define MTOT  4096      // batch * seq
#define NHEAD 16
#define DHEAD 64
#define ROPE_C 0.41524101186091903f   // log2(10000)/32
#define XN    (MTOT * DM)             // 4194304
#define WN    (DM * DM)               // 1048576
#define CVT_BLOCKS ((XN + 4 * WN) / (8 * 256))   // 4096
#define TAB_N      (SEQ * 32)                    // 65536 float2

typedef __bf16 bf16x8 __attribute__((ext_vector_type(8)));
typedef float  f32x4  __attribute__((ext_vector_type(4)));

// async global->LDS, 16 B/lane; lds dest = wave-uniform base + lane*16
__device__ __forceinline__ void gll16(const __bf16* gp, __bf16* lp) {
    __builtin_amdgcn_global_load_lds(
        (const __attribute__((address_space(1))) unsigned int*)gp,
        (__attribute__((address_space(3))) unsigned int*)lp,
        16, 0, 0);
}

// -------- fp32 -> bf16 conversion of x + 4 weights, and RoPE sin/cos table ------------
__global__ __launch_bounds__(256) void cvt_kernel(
    const float* __restrict__ x,  const float* __restrict__ wq,
    const float* __restrict__ wk, const float* __restrict__ wv,
    const float* __restrict__ wo, const int* __restrict__ pos,
    __bf16* __restrict__ xb,  __bf16* __restrict__ wqb,
    __bf16* __restrict__ wkb, __bf16* __restrict__ wvb,
    __bf16* __restrict__ wob, float2* __restrict__ sc)
{
    if (blockIdx.x >= CVT_BLOCKS) {   // sin/cos table: sc[s][ip] = (cos, sin)
        const int idx = (blockIdx.x - CVT_BLOCKS) * 256 + threadIdx.x;
        if (idx < TAB_N) {
            const int p_i = idx >> 5, ip = idx & 31;
            const float ang = (float)pos[p_i] * exp2f(-(float)ip * ROPE_C);
            float sn, cs;
            sincosf(ang, &sn, &cs);
            sc[idx] = make_float2(cs, sn);
        }
        return;
    }
    const size_t i8 = ((size_t)blockIdx.x * 256 + threadIdx.x) * 8;
    const float* s; __bf16* d; size_t off;
    if      (i8 < XN)          { s = x;  d = xb;  off = i8; }
    else if (i8 < XN + WN)     { s = wq; d = wqb; off = i8 - XN; }
    else if (i8 < XN + 2 * WN) { s = wk; d = wkb; off = i8 - XN - (size_t)WN; }
    else if (i8 < XN + 3 * WN) { s = wv; d = wvb; off = i8 - XN - 2 * (size_t)WN; }
    else                       { s = wo; d = wob; off = i8 - XN - 3 * (size_t)WN; }
    const float4 a = *(const float4*)(s + off);
    const float4 b = *(const float4*)(s + off + 4);
    __bf16 o[8] = {(__bf16)a.x, (__bf16)a.y, (__bf16)a.z, (__bf16)a.w,
                   (__bf16)b.x, (__bf16)b.y, (__bf16)b.z, (__bf16)b.w};
    *(float4*)(d + off) = *(float4*)o;
}

// ---------------- MFMA GEMM: C[M,1024] = A[M,1024] @ B[1024,1024]^T -------------------
// 128x128 tile, BK=32, 256 threads (2x2 waves, 4x4 16x16x32 MFMAs each).
// MODE 0: RoPE+0.125 bf16 (q)  MODE 1: RoPE bf16 (k)
// MODE 2: bf16 row-major (v)   MODE 3: fp32 (proj out)
template <int MODE>
__device__ __forceinline__ void mfma_gemm_body(
    __bf16* __restrict__ smem,
    const __bf16* __restrict__ A, const __bf16* __restrict__ B,
    void* __restrict__ Cv, const float2* __restrict__ sc)
{
    __bf16* As = smem;
    __bf16* Bs = smem + 4096;

    const int tid  = threadIdx.x;
    const int wave = tid >> 6, lane = tid & 63;
    const int lq   = lane & 15, quad = lane >> 4;
    const int row0 = blockIdx.y * 128, col0 = blockIdx.x * 128;
    const int mb   = (wave >> 1) * 64, nb = (wave & 1) * 64;

    const int srow = wave * 32 + (lane >> 2);
    const int scol = (lane & 3) << 3;
    const __bf16* Ag = A + (size_t)(row0 + srow) * DM + scol;
    const __bf16* Bg = B + (size_t)(col0 + srow) * DM + scol;
    __bf16* Al = As + wave * 1024;
    __bf16* Bl = Bs + wave * 1024;

    f32x4 acc[4][4] = {};

    for (int k0 = 0; k0 < DM; k0 += 32) {
        gll16(Ag + k0,           Al);
        gll16(Ag + k0 + 16 * DM, Al + 512);
        gll16(Bg + k0,           Bl);
        gll16(Bg + k0 + 16 * DM, Bl + 512);
        __syncthreads();

        bf16x8 af[4], bfr[4];
        #pragma unroll
        for (int mt = 0; mt < 4; ++mt)
            af[mt] = *(const bf16x8*)&As[(mb + mt * 16 + lq) * 32 + quad * 8];
        #pragma unroll
        for (int nt = 0; nt < 4; ++nt)
            bfr[nt] = *(const bf16x8*)&Bs[(nb + nt * 16 + lq) * 32 + quad * 8];
        #pragma unroll
        for (int mt = 0; mt < 4; ++mt)
            #pragma unroll
            for (int nt = 0; nt < 4; ++nt)
                acc[mt][nt] = __builtin_amdgcn_mfma_f32_16x16x32_bf16(
                    af[mt], bfr[nt], acc[mt][nt], 0, 0, 0);
        __syncthreads();
    }

    // ---- epilogue: acc -> LDS (wave-private) -> row-per-lane -> coalesced stores ----
    float* Ls = (float*)smem + wave * (16 * 68);
    const int erow = lane >> 2;
    const int ecol = (lane & 3) << 4;

    #pragma unroll
    for (int mt = 0; mt < 4; ++mt) {
        #pragma unroll
        for (int nt = 0; nt < 4; ++nt)
            #pragma unroll
            for (int r = 0; r < 4; ++r)
                Ls[(quad * 4 + r) * 68 + lq + 16 * nt] = acc[mt][nt][r];

        float vrow[16];
        #pragma unroll
        for (int jj = 0; jj < 4; ++jj)
            *(f32x4*)&vrow[jj * 4] = *(const f32x4*)&Ls[erow * 68 + ecol + jj * 4];

        const int grow = row0 + mb + mt * 16 + erow;
        if (MODE <= 1) {
            const float2* scp = sc + ((size_t)(grow & (SEQ - 1)) << 5) + (ecol >> 1);
            __bf16 ob[16];
            #pragma unroll
            for (int j = 0; j < 8; ++j) {
                const float2 cspr = scp[j];
                const float x1 = vrow[2 * j], x2 = vrow[2 * j + 1];
                float o0 = x1 * cspr.x - x2 * cspr.y;
                float o1 = x2 * cspr.x + x1 * cspr.y;
                if (MODE == 0) { o0 *= 0.125f; o1 *= 0.125f; }
                ob[2 * j]     = (__bf16)o0;
                ob[2 * j + 1] = (__bf16)o1;
            }
            __bf16* cp = (__bf16*)Cv + (size_t)grow * DM + col0 + nb + ecol;
            *(float4*)cp       = *(float4*)ob;
            *(float4*)(cp + 8) = *(float4*)(ob + 8);
        } else if (MODE == 2) {
            __bf16 ob[16];
            #pragma unroll
            for (int j = 0; j < 16; ++j) ob[j] = (__bf16)vrow[j];
            __bf16* cp = (__bf16*)Cv + (size_t)grow * DM + col0 + nb + ecol;
            *(float4*)cp       = *(float4*)ob;
            *(float4*)(cp + 8) = *(float4*)(ob + 8);
        } else {
            float* cp = (float*)Cv + (size_t)grow * DM + col0 + nb + ecol;
            #pragma unroll
            for (int jj = 0; jj < 4; ++jj)
                *(float4*)(cp + jj * 4) = *(float4*)&vrow[jj * 4];
        }
    }
}

__global__ __launch_bounds__(256, 4) void qkv_kernel(
    const __bf16* __restrict__ xb, const __bf16* __restrict__ wqb,
    const __bf16* __restrict__ wkb, const __bf16* __restrict__ wvb,
    __bf16* __restrict__ q, __bf16* __restrict__ k, __bf16* __restrict__ v,
    const float2* __restrict__ sc)
{
    __shared__ __align__(16) __bf16 SmemRaw[8704];   // single 17408 B allocation
    const int z = blockIdx.z;
    if (z == 0)      mfma_gemm_body<0>(SmemRaw, xb, wqb, q, sc);
    else if (z == 1) mfma_gemm_body<1>(SmemRaw, xb, wkb, k, sc);
    else             mfma_gemm_body<2>(SmemRaw, xb, wvb, v, sc);
}

__global__ __launch_bounds__(256, 4) void proj_kernel(
    const __bf16* __restrict__ aob, const __bf16* __restrict__ wob,
    float* __restrict__ out)
{
    __shared__ __align__(16) __bf16 SmemRaw[8704];
    mfma_gemm_body<3>(SmemRaw, aob, wob, out, nullptr);
}

// ---------------- V transpose: v[b][s][h*64+d] -> vt[b][h][d][s] ----------------------
__global__ __launch_bounds__(256) void vtrans_kernel(
    const __bf16* __restrict__ v, __bf16* __restrict__ vt)
{
    __shared__ __bf16 Ts[64][72];
    const int tid = threadIdx.x;
    const int s0  = blockIdx.x * 64;
    const int bh  = blockIdx.y;
    const int b = bh >> 4, h = bh & 15;

    {
        const int sl = tid >> 2, d0 = (tid & 3) << 4;
        const __bf16* gp = v + (size_t)(b * SEQ + s0 + sl) * DM + h * 64 + d0;
        *(float4*)&Ts[sl][d0]     = *(const float4*)gp;
        *(float4*)&Ts[sl][d0 + 8] = *(const float4*)(gp + 8);
    }
    __syncthreads();

    {
        const int dl = tid >> 2, sB = (tid & 3) << 4;
        __bf16 c[16];
        #pragma unroll
        for (int j = 0; j < 16; ++j) c[j] = Ts[sB + j][dl];
        __bf16* gp = vt + (size_t)(bh * 64 + dl) * SEQ + s0 + sB;
        *(float4*)gp       = *(float4*)c;
        *(float4*)(gp + 8) = *(float4*)(c + 8);
    }
}

// ---------------- MFMA flash attention v10: key-split, 8 waves, 2x occupancy ---------
// v9 RETROSPECTIVE (r3): clean registers (WRITE 8MB) but KVBLK=128 = 50.9us vs v6's
// 48.5 -> barrier amortization is NOT the constraint. Profile (Mfma 14 / VALU 23 /
// HBM 27 / Occ 18) = latency-bound at 8 waves/CU, grid-capped. Wave count was
// invariant (16 q-rows/wave, MFMA M=16 floor) -> the only way to add waves is to
// split the KEY dimension. Fixed-shift softmax (no running max) makes partial O and
// partial l PURE SUMS over key subsets -> trivially mergeable.
// v10 = v6 tile (KVBLK=64, conflict-free strides 68/76, proven 48.5us) with 512
// threads / 8 waves: waves 0-3 compute EVEN K-tiles from buffer 0, waves 4-7 ODD
// tiles from buffer 1; each group stages its own buffer (same v6 per-thread map);
// register prefetch of the group's next tile kept. Super-iters per pair =
// ceil((32-x)/2)+ceil((x+1)/2) = 17 for ALL x -> every block identical work; 512
// blocks = exactly 2/CU resident -> 16 waves/CU (2x v6). Phase-end merge: group B
// adds partial O (16 f32) + l via an LDS region overlaid on the (dead) Ks buffers,
// stride 17 dwords (odd -> conflict-free); group A merges + writes O.
// LDS 54272 B; __launch_bounds__(512,4) caps VGPR at 128 (est ~90 live).
__global__ __launch_bounds__(512, 4) void attn_kernel(
    const __bf16* __restrict__ Q, const __bf16* __restrict__ K,
    const __bf16* __restrict__ Vt, __bf16* __restrict__ O)
{
    __shared__ __align__(16) char LdsRaw[54272];
    auto Ks0 = (__bf16 (*)[68])(LdsRaw);                  //  8704 B  [64][68]
    auto Ks1 = (__bf16 (*)[68])(LdsRaw + 8704);           //  8704 B
    auto Vs0 = (__bf16 (*)[68])(LdsRaw + 17408);          //  8704 B
    auto Vs1 = (__bf16 (*)[68])(LdsRaw + 26112);          //  8704 B
    auto Ps  = (__bf16 (*)[16][76])(LdsRaw + 34816);      // [8][16][76] 19456 B
    auto Mg  = (float  (*)[64][17])(LdsRaw);              // [4][64][17] 17408 B, overlay Ks0+Ks1

    const int tid  = threadIdx.x;
    const int wave = tid >> 6;          // 0..7
    const int grp  = wave >> 2;         // 0: even tiles (buf0), 1: odd tiles (buf1)
    const int lane = tid & 63;
    const int lq   = lane & 15;
    const int quad = lane >> 4;
    const int xpair = blockIdx.x, bh = blockIdx.y;
    const int b = bh >> 4, h = bh & 15;
    const size_t qkoff = (size_t)b * SEQ * DM + h * 64;
    const size_t vtoff = (size_t)bh * 64 * SEQ;

    __bf16 (*Ksg)[68] = grp ? Ks1 : Ks0;    // wave-uniform LDS base (SGPR)
    __bf16 (*Vsg)[68] = grp ? Vs1 : Vs0;

    // staging map: within each 256-thread group, 32 B per thread per buffer
    const int t8 = tid & 255;
    const int r_ = t8 >> 2, c_ = (t8 & 3) << 4;
    const __bf16* kg = K  + qkoff + (size_t)r_ * DM  + c_;
    const __bf16* vg = Vt + vtoff + (size_t)r_ * SEQ + c_;

#define LOAD_KV(TL) do {                                                \
        const __bf16* kp_ = kg + (size_t)(TL) * 64 * DM;                \
        const __bf16* vp_ = vg + (TL) * 64;                             \
        kf0 = *(const float4*)kp_;                                      \
        kf1 = *(const float4*)(kp_ + 8);                                \
        vf0 = *(const float4*)vp_;                                      \
        vf1 = *(const float4*)(vp_ + 8);                                \
    } while (0)

#define STAGE_KV() do {                                                 \
        *(float4*)&Ksg[r_][c_]     = kf0;                               \
        *(float4*)&Ksg[r_][c_ + 8] = kf1;                               \
        *(float4*)&Vsg[r_][c_]     = vf0;                               \
        *(float4*)&Vsg[r_][c_ + 8] = vf1;                               \
    } while (0)

#define QKT(SREG, T) do {                                               \
        const bf16x8 ak0_ = *(const bf16x8*)&Ksg[(T) * 16 + lq][quad * 8];      \
        const bf16x8 ak1_ = *(const bf16x8*)&Ksg[(T) * 16 + lq][32 + quad * 8]; \
        f32x4 z_ = {};                                                  \
        z_ = __builtin_amdgcn_mfma_f32_16x16x32_bf16(ak0_, bq0, z_, 0, 0, 0);   \
        SREG = __builtin_amdgcn_mfma_f32_16x16x32_bf16(ak1_, bq1, z_, 0, 0, 0); \
    } while (0)

#define MASKT(SREG, T) do {                                             \
        const int kb_ = tg * 64 + (T) * 16 + quad * 4;                  \
        if (kb_ + 0 > myq) SREG[0] = -INFINITY;                         \
        if (kb_ + 1 > myq) SREG[1] = -INFINITY;                         \
        if (kb_ + 2 > myq) SREG[2] = -INFINITY;                         \
        if (kb_ + 3 > myq) SREG[3] = -INFINITY;                         \
    } while (0)

#define EXPST(SREG, T) do {                                             \
        __bf16 pb_[4];                                                  \
        const float e0_ = __expf(SREG[0]);                              \
        const float e1_ = __expf(SREG[1]);                              \
        const float e2_ = __expf(SREG[2]);                              \
        const float e3_ = __expf(SREG[3]);                              \
        l_part += (e0_ + e1_) + (e2_ + e3_);                            \
        pb_[0] = (__bf16)e0_; pb_[1] = (__bf16)e1_;                     \
        pb_[2] = (__bf16)e2_; pb_[3] = (__bf16)e3_;                     \
        *(float2*)&Ps[wave][lq][(T) * 16 + quad * 4] = *(float2*)pb_;   \
    } while (0)

#define PVKC(KC) do {                                                   \
        const bf16x8 ap_  = *(const bf16x8*)&Ps[wave][lq][(KC) * 32 + quad * 8]; \
        const bf16x8 bv0_ = *(const bf16x8*)&Vsg[lq]     [(KC) * 32 + quad * 8]; \
        const bf16x8 bv1_ = *(const bf16x8*)&Vsg[lq + 16][(KC) * 32 + quad * 8]; \
        const bf16x8 bv2_ = *(const bf16x8*)&Vsg[lq + 32][(KC) * 32 + quad * 8]; \
        const bf16x8 bv3_ = *(const bf16x8*)&Vsg[lq + 48][(KC) * 32 + quad * 8]; \
        oa0 = __builtin_amdgcn_mfma_f32_16x16x32_bf16(ap_, bv0_, oa0, 0, 0, 0);  \
        oa1 = __builtin_amdgcn_mfma_f32_16x16x32_bf16(ap_, bv1_, oa1, 0, 0, 0);  \
        oa2 = __builtin_amdgcn_mfma_f32_16x16x32_bf16(ap_, bv2_, oa2, 0, 0, 0);  \
        oa3 = __builtin_amdgcn_mfma_f32_16x16x32_bf16(ap_, bv3_, oa3, 0, 0, 0);  \
    } while (0)

    #pragma unroll
    for (int phase = 0; phase < 2; ++phase) {
        const int qt = phase ? xpair : (31 - xpair);
        const int row_base = qt * 64 + (wave & 3) * 16;
        const int nt   = qt + 1;
        const int nsup = (nt + 1) >> 1;      // super-iterations (2 tiles each)

        // Q fragment (B-operand): q-row = row_base + lq (pre-scaled by 1/8)
        const __bf16* qp = Q + qkoff + (size_t)(row_base + lq) * DM + quad * 8;
        const bf16x8 bq0 = *(const bf16x8*)qp;
        const bf16x8 bq1 = *(const bf16x8*)(qp + 32);

        // prime: my group's tile 0 (A: tile 0, B: tile min(1, nt-1))
        float4 kf0, kf1, vf0, vf1;
        {
            const int tl = (grp && nt > 1) ? 1 : 0;
            LOAD_KV(tl);
        }
        __syncthreads();   // previous phase's LDS reads (incl. merge reads) complete
        STAGE_KV();
        __syncthreads();

        f32x4 oa0 = {}, oa1 = {}, oa2 = {}, oa3 = {};
        float l_part = 0.f;

        for (int i = 0; i < nsup; ++i) {
            // prefetch my group's next tile into registers while computing
            if (i + 1 < nsup) {
                int tl = 2 * (i + 1) + grp;
                if (tl > nt - 1) tl = nt - 1;    // uniform clamp (B, even nt)
                LOAD_KV(tl);
            }

            const int tg = 2 * i + grp;          // my global tile index
            if (tg < nt) {                        // B idles on odd-nt last super
                f32x4 s0, s1, s2, s3;
                __builtin_amdgcn_s_setprio(1);
                QKT(s0, 0); QKT(s1, 1); QKT(s2, 2); QKT(s3, 3);
                __builtin_amdgcn_s_setprio(0);

                if (tg == nt - 1) {               // diagonal tile: causal mask
                    const int myq = row_base + lq;
                    MASKT(s0, 0); MASKT(s1, 1); MASKT(s2, 2); MASKT(s3, 3);
                }

                EXPST(s0, 0); EXPST(s1, 1); EXPST(s2, 2); EXPST(s3, 3);

                __builtin_amdgcn_s_setprio(1);
                PVKC(0); PVKC(1);
                __builtin_amdgcn_s_setprio(0);
            }

            if (i + 1 < nsup) {
                __syncthreads();   // all waves done reading Ks/Vs
                STAGE_KV();
                __syncthreads();
            }
        }

        // l: quad-copies of the same q-row live in lanes lq, lq+16, lq+32, lq+48
        l_part += __shfl_xor(l_part, 16, 64);
        l_part += __shfl_xor(l_part, 32, 64);

        // ---- merge group B partials into group A via LDS (overlaid on Ks) ----
        __syncthreads();          // everyone done reading Ks/Vs this phase
        if (grp) {
            float* mp = &Mg[wave & 3][lane][0];
            mp[0]  = oa0[0]; mp[1]  = oa0[1]; mp[2]  = oa0[2]; mp[3]  = oa0[3];
            mp[4]  = oa1[0]; mp[5]  = oa1[1]; mp[6]  = oa1[2]; mp[7]  = oa1[3];
            mp[8]  = oa2[0]; mp[9]  = oa2[1]; mp[10] = oa2[2]; mp[11] = oa2[3];
            mp[12] = oa3[0]; mp[13] = oa3[1]; mp[14] = oa3[2]; mp[15] = oa3[3];
            mp[16] = l_part;
        }
        __syncthreads();
        if (!grp) {
            const float* mp = &Mg[wave][lane][0];
            oa0[0] += mp[0];  oa0[1] += mp[1];  oa0[2] += mp[2];  oa0[3] += mp[3];
            oa1[0] += mp[4];  oa1[1] += mp[5];  oa1[2] += mp[6];  oa1[3] += mp[7];
            oa2[0] += mp[8];  oa2[1] += mp[9];  oa2[2] += mp[10]; oa2[3] += mp[11];
            oa3[0] += mp[12]; oa3[1] += mp[13]; oa3[2] += mp[14]; oa3[3] += mp[15];
            l_part += mp[16];

            // write O: o[nt][r] = O[q = row_base + quad*4 + r][d = lq + 16*nt]
            #pragma unroll
            for (int r = 0; r < 4; ++r) {
                const float lr = __shfl(l_part, quad * 4 + r, 64);
                const float invl = 1.f / lr;
                const size_t row = (size_t)b * SEQ + row_base + quad * 4 + r;
                __bf16* op = O + row * DM + h * 64 + lq;
                op[0]  = (__bf16)((r == 0 ? oa0[0] : r == 1 ? oa0[1] : r == 2 ? oa0[2] : oa0[3]) * invl);
                op[16] = (__bf16)((r == 0 ? oa1[0] : r == 1 ? oa1[1] : r == 2 ? oa1[2] : oa1[3]) * invl);
                op[32] = (__bf16)((r == 0 ? oa2[0] : r == 1 ? oa2[1] : r == 2 ? oa2[2] : oa2[3]) * invl);
                op[48] = (__bf16)((r == 0 ? oa3[0] : r == 1 ? oa3[1] : r == 2 ? oa3[2] : oa3[3]) * invl);
            }
        }
    }

#undef LOAD_KV
#undef STAGE_KV
#undef QKT
#undef MASKT
#undef EXPST
#undef PVKC
}

extern "C" void kernel_launch(void* const* d_in, const int* in_sizes, int n_in,
                              void* d_out, int out_size, void* d_ws, size_t ws_size,
                              hipStream_t stream)
{
    const float* x  = (const float*)d_in[0];
    const int*  pos = (const int*)d_in[1];
    const float* Wq = (const float*)d_in[2];
    const float* Wk = (const float*)d_in[3];
    const float* Wv = (const float*)d_in[4];
    const float* Wo = (const float*)d_in[5];
    float* out = (float*)d_out;

    __bf16* xb  = (__bf16*)d_ws;            // 8 MB
    __bf16* wqb = xb  + (size_t)XN;         // 2 MB each
    __bf16* wkb = wqb + (size_t)WN;
    __bf16* wvb = wkb + (size_t)WN;
    __bf16* wob = wvb + (size_t)WN;
    __bf16* q   = wob + (size_t)WN;         // 8 MB
    __bf16* k   = q   + (size_t)XN;         // 8 MB
    __bf16* v   = k   + (size_t)XN;         // 8 MB, row-major
    __bf16* vt  = v   + (size_t)XN;         // 8 MB, [b][h][dh][seq]
    __bf16* aob = vt  + (size_t)XN;         // 8 MB
    float2* sc  = (float2*)(aob + (size_t)XN);   // 512 KB RoPE table

    cvt_kernel<<<CVT_BLOCKS + TAB_N / 256, 256, 0, stream>>>(
        x, Wq, Wk, Wv, Wo, pos, xb, wqb, wkb, wvb, wob, sc);
    qkv_kernel<<<dim3(DM / 128, MTOT / 128, 3), 256, 0, stream>>>(
        xb, wqb, wkb, wvb, q, k, v, sc);
    vtrans_kernel<<<dim3(SEQ / 64, 2 * NHEAD), 256, 0, stream>>>(v, vt);
    attn_kernel<<<dim3(16, 2 * NHEAD), 512, 0, stream>>>(q, k, vt, aob);
    proj_kernel<<<dim3(DM / 128, MTOT / 128), 256, 0, stream>>>(aob, wob, out);
}

// Round 5
// 194.533 us; speedup vs baseline: 1.6239x; 1.6239x over previous
//
#include <hip/hip_runtime.h>
#include <math.h>

#define SEQ   2048
#define DM    1024
#define MTOT  4096      // batch * seq
#define NHEAD 16
#define DHEAD 64
#define ROPE_C 0.41524101186091903f   // log2(10000)/32
#define XN    (MTOT * DM)             // 4194304
#define WN    (DM * DM)               // 1048576
#define CVT_BLOCKS ((XN + 4 * WN) / (8 * 256))   // 4096
#define TAB_N      (SEQ * 32)                    // 65536 float2

typedef __bf16 bf16x8 __attribute__((ext_vector_type(8)));
typedef float  f32x4  __attribute__((ext_vector_type(4)));

// async global->LDS, 16 B/lane; lds dest = wave-uniform base + lane*16
__device__ __forceinline__ void gll16(const __bf16* gp, __bf16* lp) {
    __builtin_amdgcn_global_load_lds(
        (const __attribute__((address_space(1))) unsigned int*)gp,
        (__attribute__((address_space(3))) unsigned int*)lp,
        16, 0, 0);
}

// -------- fp32 -> bf16 conversion of x + 4 weights, and RoPE sin/cos table ------------
__global__ __launch_bounds__(256) void cvt_kernel(
    const float* __restrict__ x,  const float* __restrict__ wq,
    const float* __restrict__ wk, const float* __restrict__ wv,
    const float* __restrict__ wo, const int* __restrict__ pos,
    __bf16* __restrict__ xb,  __bf16* __restrict__ wqb,
    __bf16* __restrict__ wkb, __bf16* __restrict__ wvb,
    __bf16* __restrict__ wob, float2* __restrict__ sc)
{
    if (blockIdx.x >= CVT_BLOCKS) {   // sin/cos table: sc[s][ip] = (cos, sin)
        const int idx = (blockIdx.x - CVT_BLOCKS) * 256 + threadIdx.x;
        if (idx < TAB_N) {
            const int p_i = idx >> 5, ip = idx & 31;
            const float ang = (float)pos[p_i] * exp2f(-(float)ip * ROPE_C);
            float sn, cs;
            sincosf(ang, &sn, &cs);
            sc[idx] = make_float2(cs, sn);
        }
        return;
    }
    const size_t i8 = ((size_t)blockIdx.x * 256 + threadIdx.x) * 8;
    const float* s; __bf16* d; size_t off;
    if      (i8 < XN)          { s = x;  d = xb;  off = i8; }
    else if (i8 < XN + WN)     { s = wq; d = wqb; off = i8 - XN; }
    else if (i8 < XN + 2 * WN) { s = wk; d = wkb; off = i8 - XN - (size_t)WN; }
    else if (i8 < XN + 3 * WN) { s = wv; d = wvb; off = i8 - XN - 2 * (size_t)WN; }
    else                       { s = wo; d = wob; off = i8 - XN - 3 * (size_t)WN; }
    const float4 a = *(const float4*)(s + off);
    const float4 b = *(const float4*)(s + off + 4);
    __bf16 o[8] = {(__bf16)a.x, (__bf16)a.y, (__bf16)a.z, (__bf16)a.w,
                   (__bf16)b.x, (__bf16)b.y, (__bf16)b.z, (__bf16)b.w};
    *(float4*)(d + off) = *(float4*)o;
}

// ---------------- MFMA GEMM: C[M,1024] = A[M,1024] @ B[1024,1024]^T -------------------
// 128x128 tile, BK=32, 256 threads (2x2 waves, 4x4 16x16x32 MFMAs each).
// MODE 0: RoPE+0.125 bf16 (q)  MODE 1: RoPE bf16 (k)
// MODE 2: bf16 row-major (v)   MODE 3: fp32 (proj out)
// kbeg/kend: K-range (split-K support for proj; qkv passes 0..DM)
template <int MODE>
__device__ __forceinline__ void mfma_gemm_body(
    __bf16* __restrict__ smem,
    const __bf16* __restrict__ A, const __bf16* __restrict__ B,
    void* __restrict__ Cv, const float2* __restrict__ sc,
    const int kbeg, const int kend)
{
    __bf16* As = smem;
    __bf16* Bs = smem + 4096;

    const int tid  = threadIdx.x;
    const int wave = tid >> 6, lane = tid & 63;
    const int lq   = lane & 15, quad = lane >> 4;
    const int row0 = blockIdx.y * 128, col0 = blockIdx.x * 128;
    const int mb   = (wave >> 1) * 64, nb = (wave & 1) * 64;

    const int srow = wave * 32 + (lane >> 2);
    const int scol = (lane & 3) << 3;
    const __bf16* Ag = A + (size_t)(row0 + srow) * DM + scol;
    const __bf16* Bg = B + (size_t)(col0 + srow) * DM + scol;
    __bf16* Al = As + wave * 1024;
    __bf16* Bl = Bs + wave * 1024;

    f32x4 acc[4][4] = {};

    for (int k0 = kbeg; k0 < kend; k0 += 32) {
        gll16(Ag + k0,           Al);
        gll16(Ag + k0 + 16 * DM, Al + 512);
        gll16(Bg + k0,           Bl);
        gll16(Bg + k0 + 16 * DM, Bl + 512);
        __syncthreads();

        bf16x8 af[4], bfr[4];
        #pragma unroll
        for (int mt = 0; mt < 4; ++mt)
            af[mt] = *(const bf16x8*)&As[(mb + mt * 16 + lq) * 32 + quad * 8];
        #pragma unroll
        for (int nt = 0; nt < 4; ++nt)
            bfr[nt] = *(const bf16x8*)&Bs[(nb + nt * 16 + lq) * 32 + quad * 8];
        #pragma unroll
        for (int mt = 0; mt < 4; ++mt)
            #pragma unroll
            for (int nt = 0; nt < 4; ++nt)
                acc[mt][nt] = __builtin_amdgcn_mfma_f32_16x16x32_bf16(
                    af[mt], bfr[nt], acc[mt][nt], 0, 0, 0);
        __syncthreads();
    }

    // ---- epilogue: acc -> LDS (wave-private) -> row-per-lane -> coalesced stores ----
    float* Ls = (float*)smem + wave * (16 * 68);
    const int erow = lane >> 2;
    const int ecol = (lane & 3) << 4;

    #pragma unroll
    for (int mt = 0; mt < 4; ++mt) {
        #pragma unroll
        for (int nt = 0; nt < 4; ++nt)
            #pragma unroll
            for (int r = 0; r < 4; ++r)
                Ls[(quad * 4 + r) * 68 + lq + 16 * nt] = acc[mt][nt][r];

        float vrow[16];
        #pragma unroll
        for (int jj = 0; jj < 4; ++jj)
            *(f32x4*)&vrow[jj * 4] = *(const f32x4*)&Ls[erow * 68 + ecol + jj * 4];

        const int grow = row0 + mb + mt * 16 + erow;
        if (MODE <= 1) {
            const float2* scp = sc + ((size_t)(grow & (SEQ - 1)) << 5) + (ecol >> 1);
            __bf16 ob[16];
            #pragma unroll
            for (int j = 0; j < 8; ++j) {
                const float2 cspr = scp[j];
                const float x1 = vrow[2 * j], x2 = vrow[2 * j + 1];
                float o0 = x1 * cspr.x - x2 * cspr.y;
                float o1 = x2 * cspr.x + x1 * cspr.y;
                if (MODE == 0) { o0 *= 0.125f; o1 *= 0.125f; }
                ob[2 * j]     = (__bf16)o0;
                ob[2 * j + 1] = (__bf16)o1;
            }
            __bf16* cp = (__bf16*)Cv + (size_t)grow * DM + col0 + nb + ecol;
            *(float4*)cp       = *(float4*)ob;
            *(float4*)(cp + 8) = *(float4*)(ob + 8);
        } else if (MODE == 2) {
            __bf16 ob[16];
            #pragma unroll
            for (int j = 0; j < 16; ++j) ob[j] = (__bf16)vrow[j];
            __bf16* cp = (__bf16*)Cv + (size_t)grow * DM + col0 + nb + ecol;
            *(float4*)cp       = *(float4*)ob;
            *(float4*)(cp + 8) = *(float4*)(ob + 8);
        } else {
            float* cp = (float*)Cv + (size_t)grow * DM + col0 + nb + ecol;
            #pragma unroll
            for (int jj = 0; jj < 4; ++jj)
                *(float4*)(cp + jj * 4) = *(float4*)&vrow[jj * 4];
        }
    }
}

__global__ __launch_bounds__(256, 4) void qkv_kernel(
    const __bf16* __restrict__ xb, const __bf16* __restrict__ wqb,
    const __bf16* __restrict__ wkb, const __bf16* __restrict__ wvb,
    __bf16* __restrict__ q, __bf16* __restrict__ k, __bf16* __restrict__ v,
    const float2* __restrict__ sc)
{
    __shared__ __align__(16) __bf16 SmemRaw[8704];   // single 17408 B allocation
    const int z = blockIdx.z;
    if (z == 0)      mfma_gemm_body<0>(SmemRaw, xb, wqb, q, sc, 0, DM);
    else if (z == 1) mfma_gemm_body<1>(SmemRaw, xb, wkb, k, sc, 0, DM);
    else             mfma_gemm_body<2>(SmemRaw, xb, wvb, v, sc, 0, DM);
}

// proj split-K=2: z=0 computes k[0,512) -> out, z=1 computes k[512,1024) -> p1.
// 512 blocks -> 2 blocks/CU (vs 1 before: grid-capped occupancy was the limiter).
__global__ __launch_bounds__(256, 4) void proj_kernel(
    const __bf16* __restrict__ aob, const __bf16* __restrict__ wob,
    float* __restrict__ out, float* __restrict__ p1)
{
    __shared__ __align__(16) __bf16 SmemRaw[8704];
    if (blockIdx.z == 0) mfma_gemm_body<3>(SmemRaw, aob, wob, out, nullptr, 0, 512);
    else                 mfma_gemm_body<3>(SmemRaw, aob, wob, p1,  nullptr, 512, 1024);
}

// out += p1  (float4 per thread; 4096 blocks x 256 threads x 4 floats = 4M)
__global__ __launch_bounds__(256) void merge_kernel(
    float* __restrict__ out, const float* __restrict__ p1)
{
    const size_t i = ((size_t)blockIdx.x * 256 + threadIdx.x) * 4;
    float4 a = *(float4*)(out + i);
    const float4 b = *(const float4*)(p1 + i);
    a.x += b.x; a.y += b.y; a.z += b.z; a.w += b.w;
    *(float4*)(out + i) = a;
}

// ---------------- V transpose: v[b][s][h*64+d] -> vt[b][h][d][s] ----------------------
__global__ __launch_bounds__(256) void vtrans_kernel(
    const __bf16* __restrict__ v, __bf16* __restrict__ vt)
{
    __shared__ __bf16 Ts[64][72];
    const int tid = threadIdx.x;
    const int s0  = blockIdx.x * 64;
    const int bh  = blockIdx.y;
    const int b = bh >> 4, h = bh & 15;

    {
        const int sl = tid >> 2, d0 = (tid & 3) << 4;
        const __bf16* gp = v + (size_t)(b * SEQ + s0 + sl) * DM + h * 64 + d0;
        *(float4*)&Ts[sl][d0]     = *(const float4*)gp;
        *(float4*)&Ts[sl][d0 + 8] = *(const float4*)(gp + 8);
    }
    __syncthreads();

    {
        const int dl = tid >> 2, sB = (tid & 3) << 4;
        __bf16 c[16];
        #pragma unroll
        for (int j = 0; j < 16; ++j) c[j] = Ts[sB + j][dl];
        __bf16* gp = vt + (size_t)(bh * 64 + dl) * SEQ + s0 + sB;
        *(float4*)gp       = *(float4*)c;
        *(float4*)(gp + 8) = *(float4*)(c + 8);
    }
}

// ---------------- MFMA flash attention v11 = v6 (proven 48.5us) + XCD swizzle --------
// v10 RETROSPECTIVE (r4): doubling waves via key-split made it 3.5x SLOWER (Occ 41%
// but Mfma 4%/VALU 7%) -> wave count was never the resource. Three structural probes
// (KVBLK=128 x2, key-split) all lost to v6 -> v6 structure is final.
// What r0 counters DO show: FETCH=97MB vs ~32MB unique data. K/V of one (b,h)
// (512 KB) is re-read by 16 xpair-blocks scattered across 8 XCDs -> every tile load
// is an L2 MISS (~900cy) with only 2 waves/SIMD to hide it. Fix: 1-D grid remapped
// so all 16 blocks of a bh land on ONE XCD (gid%8 == bh%8; per-XCD set: 4 bh x
// 512 KB = 2 MB <= 4 MB L2). Pure index remap; no sync/structure change.
__global__ __launch_bounds__(256, 2) void attn_kernel(
    const __bf16* __restrict__ Q, const __bf16* __restrict__ K,
    const __bf16* __restrict__ Vt, __bf16* __restrict__ O)
{
    __shared__ __bf16 Ks[64][68];       // [key][dh]
    __shared__ __bf16 Vs[64][68];       // [dh][key]
    __shared__ __bf16 Ps[4][16][76];    // wave-private P[qrow][key]

    const int tid  = threadIdx.x;
    const int wave = tid >> 6;
    const int lane = tid & 63;
    const int lq   = lane & 15;
    const int quad = lane >> 4;
    // XCD-locality remap: gid = (bh&7) + 8*((xpair<<2) | (bh>>3))  (bijective, 512)
    const int gid   = blockIdx.x;
    const int xpair = gid >> 5;
    const int bh    = (gid & 7) + (((gid >> 3) & 3) << 3);
    const int b = bh >> 4, h = bh & 15;
    const size_t qkoff = (size_t)b * SEQ * DM + h * 64;
    const size_t vtoff = (size_t)bh * 64 * SEQ;

    // staging map: 32 B per thread per buffer (64 rows x 64 cols bf16)
    const int r_ = tid >> 2, c_ = (tid & 3) << 4;
    const __bf16* kg = K  + qkoff + (size_t)r_ * DM  + c_;
    const __bf16* vg = Vt + vtoff + (size_t)r_ * SEQ + c_;

    #pragma unroll
    for (int phase = 0; phase < 2; ++phase) {
        const int qt = phase ? xpair : (31 - xpair);
        const int row_base = qt * 64 + wave * 16;
        const int ntiles = qt + 1;

        // Q fragment (B-operand): q-row = row_base + lq (pre-scaled by 1/8)
        const __bf16* qp = Q + qkoff + (size_t)(row_base + lq) * DM + quad * 8;
        const bf16x8 bq0 = *(const bf16x8*)qp;
        const bf16x8 bq1 = *(const bf16x8*)(qp + 32);

        // prime: tile 0 into registers
        float4 k0 = *(const float4*)kg, k1 = *(const float4*)(kg + 8);
        float4 v0 = *(const float4*)vg, v1 = *(const float4*)(vg + 8);

        __syncthreads();   // previous phase's LDS reads complete
        *(float4*)&Ks[r_][c_]     = k0;
        *(float4*)&Ks[r_][c_ + 8] = k1;
        *(float4*)&Vs[r_][c_]     = v0;
        *(float4*)&Vs[r_][c_ + 8] = v1;
        __syncthreads();

        f32x4 o[4] = {};
        float l_part = 0.f;

        for (int kt = 0; kt < ntiles; ++kt) {
            // prefetch next tile into registers while computing this one
            if (kt + 1 < ntiles) {
                const __bf16* kp = kg + (size_t)(kt + 1) * 64 * DM;
                const __bf16* vp = vg + (kt + 1) * 64;
                k0 = *(const float4*)kp; k1 = *(const float4*)(kp + 8);
                v0 = *(const float4*)vp; v1 = *(const float4*)(vp + 8);
            }

            // S^T: lane -> q-row = row_base+lq, keys kt*64 + t*16 + quad*4 + r
            f32x4 s[4];
            #pragma unroll
            for (int t = 0; t < 4; ++t) {
                const bf16x8 ak0 = *(const bf16x8*)&Ks[t * 16 + lq][quad * 8];
                const bf16x8 ak1 = *(const bf16x8*)&Ks[t * 16 + lq][32 + quad * 8];
                f32x4 z = {};
                z = __builtin_amdgcn_mfma_f32_16x16x32_bf16(ak0, bq0, z, 0, 0, 0);
                s[t] = __builtin_amdgcn_mfma_f32_16x16x32_bf16(ak1, bq1, z, 0, 0, 0);
            }

            if (kt == qt) {    // diagonal tile: causal mask (key > q-row)
                const int myq = row_base + lq;
                #pragma unroll
                for (int t = 0; t < 4; ++t) {
                    const int kb = kt * 64 + t * 16 + quad * 4;
                    #pragma unroll
                    for (int r = 0; r < 4; ++r)
                        if (kb + r > myq) s[t][r] = -INFINITY;
                }
            }

            // fixed-shift softmax: P = exp(s); pack 4 consecutive keys -> b64 store
            #pragma unroll
            for (int t = 0; t < 4; ++t) {
                __bf16 pb[4];
                #pragma unroll
                for (int r = 0; r < 4; ++r) {
                    const float e = __expf(s[t][r]);
                    l_part += e;
                    pb[r] = (__bf16)e;
                }
                *(float2*)&Ps[wave][lq][t * 16 + quad * 4] = *(float2*)pb;
            }

            // O = P V  (A = P rows, B = V^T rows), keys in 2 chunks of 32
            #pragma unroll
            for (int kc = 0; kc < 2; ++kc) {
                const bf16x8 ap = *(const bf16x8*)&Ps[wave][lq][kc * 32 + quad * 8];
                #pragma unroll
                for (int nt = 0; nt < 4; ++nt) {
                    const bf16x8 bv = *(const bf16x8*)&Vs[lq + 16 * nt][kc * 32 + quad * 8];
                    o[nt] = __builtin_amdgcn_mfma_f32_16x16x32_bf16(ap, bv, o[nt], 0, 0, 0);
                }
            }

            if (kt + 1 < ntiles) {
                __syncthreads();   // all waves done reading Ks/Vs
                *(float4*)&Ks[r_][c_]     = k0;
                *(float4*)&Ks[r_][c_ + 8] = k1;
                *(float4*)&Vs[r_][c_]     = v0;
                *(float4*)&Vs[r_][c_ + 8] = v1;
                __syncthreads();
            }
        }

        // l: quad-copies of the same q-row live in lanes lq, lq+16, lq+32, lq+48
        l_part += __shfl_xor(l_part, 16, 64);
        l_part += __shfl_xor(l_part, 32, 64);

        // write O: o[nt][r] = O[q = row_base + quad*4 + r][d = lq + 16*nt]
        #pragma unroll
        for (int r = 0; r < 4; ++r) {
            const float lr = __shfl(l_part, quad * 4 + r, 64);
            const float invl = 1.f / lr;
            const size_t row = (size_t)b * SEQ + row_base + quad * 4 + r;
            __bf16* op = O + row * DM + h * 64 + lq;
            #pragma unroll
            for (int nt = 0; nt < 4; ++nt)
                op[16 * nt] = (__bf16)(o[nt][r] * invl);
        }
    }
}

extern "C" void kernel_launch(void* const* d_in, const int* in_sizes, int n_in,
                              void* d_out, int out_size, void* d_ws, size_t ws_size,
                              hipStream_t stream)
{
    const float* x  = (const float*)d_in[0];
    const int*  pos = (const int*)d_in[1];
    const float* Wq = (const float*)d_in[2];
    const float* Wk = (const float*)d_in[3];
    const float* Wv = (const float*)d_in[4];
    const float* Wo = (const float*)d_in[5];
    float* out = (float*)d_out;

    __bf16* xb  = (__bf16*)d_ws;            // 8 MB
    __bf16* wqb = xb  + (size_t)XN;         // 2 MB each
    __bf16* wkb = wqb + (size_t)WN;
    __bf16* wvb = wkb + (size_t)WN;
    __bf16* wob = wvb + (size_t)WN;
    __bf16* q   = wob + (size_t)WN;         // 8 MB
    __bf16* k   = q   + (size_t)XN;         // 8 MB
    __bf16* v   = k   + (size_t)XN;         // 8 MB, row-major
    __bf16* vt  = v   + (size_t)XN;         // 8 MB, [b][h][dh][seq]
    __bf16* aob = vt  + (size_t)XN;         // 8 MB
    float2* sc  = (float2*)(aob + (size_t)XN);   // 512 KB RoPE table
    // proj K-half-1 partial: f32 [4096][1024] = 16.78 MB, overlaid on q+k
    // (q,k dead once attn completes; proj runs after attn)
    float* p1   = (float*)q;

    cvt_kernel<<<CVT_BLOCKS + TAB_N / 256, 256, 0, stream>>>(
        x, Wq, Wk, Wv, Wo, pos, xb, wqb, wkb, wvb, wob, sc);
    qkv_kernel<<<dim3(DM / 128, MTOT / 128, 3), 256, 0, stream>>>(
        xb, wqb, wkb, wvb, q, k, v, sc);
    vtrans_kernel<<<dim3(SEQ / 64, 2 * NHEAD), 256, 0, stream>>>(v, vt);
    attn_kernel<<<dim3(512), 256, 0, stream>>>(q, k, vt, aob);
    proj_kernel<<<dim3(DM / 128, MTOT / 128, 2), 256, 0, stream>>>(aob, wob, out, p1);
    merge_kernel<<<dim3(XN / (4 * 256)), 256, 0, stream>>>(out, p1);
}